// Round 2
// baseline (156.044 us; speedup 1.0000x reference)
//
#include <hip/hip_runtime.h>

#define N_NODES 50000
#define K_DEG   17
#define DIN     128
#define DOUT    64
#define XPAD    4                     // Xl row stride = DIN+XPAD = 132 -> 2-way banks
#define GROWS   64                    // rows per gemm block

// ---------------------------------------------------------------------------
// Batcher merge-exchange sorting network (compile-time; fully unrolls).
// ---------------------------------------------------------------------------
struct CEPair { unsigned char a, b; };

constexpr int net_count(int n) {
  int t = 0; while ((1 << t) < n) ++t;
  int cnt = 0;
  for (int p = 1 << (t - 1); p > 0; p >>= 1) {
    int q = 1 << (t - 1), r = 0, d = p;
    for (;;) {
      for (int i = 0; i < n - d; ++i)
        if ((i & p) == r) ++cnt;
      if (q == p) break;
      d = q - p; q >>= 1; r = p;
    }
  }
  return cnt;
}

template <int NP>
struct NetArr { CEPair v[NP]; };

template <int NP>
constexpr NetArr<NP> net_pairs(int n) {
  NetArr<NP> out{};
  int t = 0; while ((1 << t) < n) ++t;
  int cnt = 0;
  for (int p = 1 << (t - 1); p > 0; p >>= 1) {
    int q = 1 << (t - 1), r = 0, d = p;
    for (;;) {
      for (int i = 0; i < n - d; ++i)
        if ((i & p) == r) {
          out.v[cnt].a = (unsigned char)i;
          out.v[cnt].b = (unsigned char)(i + d);
          ++cnt;
        }
      if (q == p) break;
      d = q - p; q >>= 1; r = p;
    }
  }
  return out;
}

constexpr int NP17 = net_count(K_DEG);   // 74 compare-exchanges for n=17

// ---------------------------------------------------------------------------
// Kernel 1: xp = x @ W. Both operands staged in LDS (x was 16x-redundantly
// re-read from global in R1 -> suspected 45-90us). 4 dims x 4 rows / thread.
// LDS: Wl 32KB + Xl 33.8KB = 65.8KB -> 2 blocks/CU.
// ---------------------------------------------------------------------------
__global__ __launch_bounds__(256) void gemm_kernel(
    const float* __restrict__ x, const float* __restrict__ W,
    float* __restrict__ xp) {
  __shared__ float Wl[DIN * DOUT];            // [k][dout], 32 KB
  __shared__ float Xl[GROWS * (DIN + XPAD)];  // [row][k], stride 132, 33.8 KB

  const int t = threadIdx.x;
  const int block_r0 = blockIdx.x * GROWS;

  // stage W: 2048 float4 / 256 threads = 8 each, coalesced
  {
    const float4* Wg4 = (const float4*)W;
    float4* Wl4 = (float4*)Wl;
    #pragma unroll
    for (int i = 0; i < 8; ++i)
      Wl4[t + i * 256] = Wg4[t + i * 256];
  }
  // stage x tile: 64 rows x 128 = 2048 float4 / 256 threads = 8 each
  {
    const float4* x4 = (const float4*)x;
    #pragma unroll
    for (int i = 0; i < 8; ++i) {
      int flat = t + i * 256;     // float4 index within tile
      int r    = flat >> 5;       // 0..63
      int kc   = flat & 31;       // 0..31
      int gr   = block_r0 + r;
      if (gr >= N_NODES) gr = N_NODES - 1;   // clamp tail (junk, never stored)
      float4 val = x4[gr * (DIN / 4) + kc];
      *(float4*)&Xl[r * (DIN + XPAD) + kc * 4] = val;
    }
  }
  __syncthreads();

  const int d0 = (t & 15) * 4;    // 4 consecutive output dims
  const int r0 = (t >> 4) * 4;    // 4 consecutive rows within tile

  float4 acc[4];
  #pragma unroll
  for (int rr = 0; rr < 4; ++rr) acc[rr] = make_float4(0.f, 0.f, 0.f, 0.f);

  #pragma unroll 4
  for (int kc = 0; kc < DIN / 4; ++kc) {
    float4 xv[4];
    #pragma unroll
    for (int rr = 0; rr < 4; ++rr)
      xv[rr] = *(const float4*)&Xl[(r0 + rr) * (DIN + XPAD) + kc * 4];
    #pragma unroll
    for (int kk = 0; kk < 4; ++kk) {
      float4 wv = *(const float4*)&Wl[(kc * 4 + kk) * DOUT + d0];
      #pragma unroll
      for (int rr = 0; rr < 4; ++rr) {
        float xs = (kk == 0) ? xv[rr].x : (kk == 1) ? xv[rr].y
                 : (kk == 2) ? xv[rr].z : xv[rr].w;
        acc[rr].x += xs * wv.x;
        acc[rr].y += xs * wv.y;
        acc[rr].z += xs * wv.z;
        acc[rr].w += xs * wv.w;
      }
    }
  }
  #pragma unroll
  for (int rr = 0; rr < 4; ++rr) {
    int r = block_r0 + r0 + rr;
    if (r < N_NODES) *(float4*)&xp[r * DOUT + d0] = acc[rr];
  }
}

// ---------------------------------------------------------------------------
// Kernel 2: per-node per-dim weighted median + row_sum scale + bias.
// One wave per node; lane = output dim. node scalarized via readfirstlane so
// cp/wp loads are uniform (SMEM-able) and gather bases are SGPR pairs.
// Summation order replicates the reference exactly: cumsum sequential in
// ascending sorted order, total = last cum, row_sum in original edge order.
// ---------------------------------------------------------------------------
__global__ __launch_bounds__(256) void median_kernel(
    const float* __restrict__ xp, const int* __restrict__ col,
    const float* __restrict__ ew, const float* __restrict__ bias,
    float* __restrict__ out) {
  const int wave = threadIdx.x >> 6;
  const int lane = threadIdx.x & 63;
  int node = blockIdx.x * 4 + wave;
  if (node >= N_NODES) return;
  node = __builtin_amdgcn_readfirstlane(node);   // wave-uniform -> SGPR

  const int*   cp = col + node * K_DEG;
  const float* wp = ew  + node * K_DEG;

  // neighbor indices -> SGPRs (enables SGPR-base gather addressing)
  int cidx[K_DEG];
  #pragma unroll
  for (int j = 0; j < K_DEG; ++j)
    cidx[j] = __builtin_amdgcn_readfirstlane(cp[j]);

  // issue all gathers early; each is a 256B coalesced row read
  float v[K_DEG];
  #pragma unroll
  for (int j = 0; j < K_DEG; ++j)
    v[j] = xp[(size_t)cidx[j] * DOUT + lane];

  float w[K_DEG];
  #pragma unroll
  for (int j = 0; j < K_DEG; ++j) w[j] = wp[j];

  // row_sum: original edge order (matches segment_sum)
  float rs = 0.f;
  #pragma unroll
  for (int j = 0; j < K_DEG; ++j) rs += w[j];

  // sort (v,w) pairs by v ascending — compile-time Batcher network
  constexpr NetArr<NP17> NET = net_pairs<NP17>(K_DEG);
  #pragma unroll
  for (int s = 0; s < NP17; ++s) {
    const int a = NET.v[s].a, b = NET.v[s].b;
    float va = v[a], vb = v[b];
    bool sw = vb < va;
    float wa = w[a], wb = w[b];
    v[a] = sw ? vb : va;  v[b] = sw ? va : vb;
    w[a] = sw ? wb : wa;  w[b] = sw ? wa : wb;
  }

  // sequential cumsum in sorted order (exact reference order)
  float c[K_DEG];
  float run = 0.f;
  #pragma unroll
  for (int j = 0; j < K_DEG; ++j) { run += w[j]; c[j] = run; }
  const float half = 0.5f * run;   // run == total == cum[-1]

  // first sorted position with cum >= half: backward cndmask scan
  float med = v[K_DEG - 1];
  #pragma unroll
  for (int j = K_DEG - 2; j >= 0; --j)
    med = (c[j] >= half) ? v[j] : med;

  out[node * DOUT + lane] = rs * med + bias[lane];
}

// ---------------------------------------------------------------------------
extern "C" void kernel_launch(void* const* d_in, const int* in_sizes, int n_in,
                              void* d_out, int out_size, void* d_ws, size_t ws_size,
                              hipStream_t stream) {
  const float* x    = (const float*)d_in[0];
  const int*   ei   = (const int*)d_in[1];
  const float* ew   = (const float*)d_in[2];
  const float* W    = (const float*)d_in[3];
  const float* bias = (const float*)d_in[4];
  float*       out  = (float*)d_out;
  float*       xp   = (float*)d_ws;                  // 50000*64*4 = 12.8 MB
  const int*   colp = ei + (size_t)N_NODES * K_DEG;  // edge_index[1]

  gemm_kernel<<<(N_NODES + GROWS - 1) / GROWS, 256, 0, stream>>>(x, W, xp);
  median_kernel<<<(N_NODES + 3) / 4, 256, 0, stream>>>(xp, colp, ew, bias, out);
}

// Round 3
// 131.336 us; speedup vs baseline: 1.1881x; 1.1881x over previous
//
#include <hip/hip_runtime.h>

#define N_NODES 50000
#define K_DEG   17
#define DIN     128
#define DOUT    64
#define KP      136   // Wht k-stride (bf16 elems): 272B rows -> 4n%32 banks, 2-way = free

typedef __attribute__((ext_vector_type(8))) short  short8;   // bf16 A/B frag (4 VGPR)
typedef __attribute__((ext_vector_type(4))) float  floatx4;  // C/D frag

// ---------------------------------------------------------------------------
// Batcher merge-exchange sorting network (compile-time; fully unrolls).
// ---------------------------------------------------------------------------
struct CEPair { unsigned char a, b; };

constexpr int net_count(int n) {
  int t = 0; while ((1 << t) < n) ++t;
  int cnt = 0;
  for (int p = 1 << (t - 1); p > 0; p >>= 1) {
    int q = 1 << (t - 1), r = 0, d = p;
    for (;;) {
      for (int i = 0; i < n - d; ++i)
        if ((i & p) == r) ++cnt;
      if (q == p) break;
      d = q - p; q >>= 1; r = p;
    }
  }
  return cnt;
}

template <int NP> struct NetArr { CEPair v[NP]; };

template <int NP>
constexpr NetArr<NP> net_pairs(int n) {
  NetArr<NP> out{};
  int t = 0; while ((1 << t) < n) ++t;
  int cnt = 0;
  for (int p = 1 << (t - 1); p > 0; p >>= 1) {
    int q = 1 << (t - 1), r = 0, d = p;
    for (;;) {
      for (int i = 0; i < n - d; ++i)
        if ((i & p) == r) {
          out.v[cnt].a = (unsigned char)i;
          out.v[cnt].b = (unsigned char)(i + d);
          ++cnt;
        }
      if (q == p) break;
      d = q - p; q >>= 1; r = p;
    }
  }
  return out;
}

constexpr int NP17 = net_count(K_DEG);   // 74 compare-exchanges for n=17

// ---------------------------------------------------------------------------
// bf16 helpers (RNE, bit-exact, finite data)
// ---------------------------------------------------------------------------
__device__ __forceinline__ unsigned int f2bf(float f) {
  union { float f; unsigned int u; } c; c.f = f;
  return (c.u + 0x7FFFu + ((c.u >> 16) & 1u)) >> 16;
}
__device__ __forceinline__ float bf2f(unsigned int b) {
  union { float f; unsigned int u; } c; c.u = b << 16;
  return c.f;
}

// ---------------------------------------------------------------------------
// Kernel 1: xp = x @ W via bf16 MFMA, 3-term hi/lo split (rel err ~2^-16).
// Wave = 16 rows x 64 dims. A: direct global fp32 loads + in-reg convert
// (x read exactly once). B: W converted per block into LDS, transposed
// [n][k] bf16, k-stride KP=136 -> b128 frag reads, 2-way banks (free).
// 50000 = 3125*16 exactly -> no row tail.
// ---------------------------------------------------------------------------
__global__ __launch_bounds__(256) void gemm_kernel(
    const float* __restrict__ x, const float* __restrict__ W,
    float* __restrict__ xp) {
  __shared__ unsigned short Wht[DOUT * KP];   // hi bf16, [n][k]
  __shared__ unsigned short Wlt[DOUT * KP];   // lo bf16, [n][k]

  const int t = threadIdx.x;

  // --- stage W: 2048 float4, coalesced; convert + transposed b16 writes ---
  {
    const float4* Wg4 = (const float4*)W;
    #pragma unroll
    for (int i = 0; i < 8; ++i) {
      int fi  = t + i * 256;        // float4 index
      int idx = fi * 4;             // flat float index
      int k   = idx >> 6;           // W is [k][n], DOUT=64
      int n0  = idx & 63;
      float4 wv = Wg4[fi];
      float  f[4] = {wv.x, wv.y, wv.z, wv.w};
      #pragma unroll
      for (int e = 0; e < 4; ++e) {
        unsigned int hb = f2bf(f[e]);
        float        lo = f[e] - bf2f(hb);
        unsigned int lb = f2bf(lo);
        Wht[(n0 + e) * KP + k] = (unsigned short)hb;
        Wlt[(n0 + e) * KP + k] = (unsigned short)lb;
      }
    }
  }
  __syncthreads();

  const int wid   = t >> 6;
  const int lane  = t & 63;
  const int gwave = blockIdx.x * 4 + wid;
  if (gwave >= (N_NODES / 16)) return;       // 3125 waves; barrier already passed

  const int r0 = gwave * 16;
  const int m  = lane & 15;                  // row within tile
  const int q  = lane >> 4;                  // k-quad 0..3

  // --- load this wave's x rows: 8 float4 = 32 floats per lane ---
  const float4* x4 = (const float4*)x;
  float4 xr[8];
  #pragma unroll
  for (int ks = 0; ks < 4; ++ks) {
    int base = (r0 + m) * (DIN / 4) + ks * 8 + q * 2;
    xr[ks * 2 + 0] = x4[base + 0];
    xr[ks * 2 + 1] = x4[base + 1];
  }

  floatx4 acc[4];
  #pragma unroll
  for (int nt = 0; nt < 4; ++nt) acc[nt] = (floatx4){0.f, 0.f, 0.f, 0.f};

  const int nb = lane & 15;                  // B-frag col within n-tile

  #pragma unroll
  for (int ks = 0; ks < 4; ++ks) {
    // build A hi/lo frags: k = ks*32 + q*8 + j, j=0..7
    float f[8] = {xr[ks*2].x, xr[ks*2].y, xr[ks*2].z, xr[ks*2].w,
                  xr[ks*2+1].x, xr[ks*2+1].y, xr[ks*2+1].z, xr[ks*2+1].w};
    union { unsigned int i[4]; short8 s; } Ah, Al;
    #pragma unroll
    for (int r = 0; r < 4; ++r) {
      unsigned int h0 = f2bf(f[2*r]),   h1 = f2bf(f[2*r+1]);
      unsigned int l0 = f2bf(f[2*r]   - bf2f(h0));
      unsigned int l1 = f2bf(f[2*r+1] - bf2f(h1));
      Ah.i[r] = h0 | (h1 << 16);
      Al.i[r] = l0 | (l1 << 16);
    }
    const int kk = ks * 32 + q * 8;
    #pragma unroll
    for (int nt = 0; nt < 4; ++nt) {
      const int n = nt * 16 + nb;
      short8 Bh = *(const short8*)&Wht[n * KP + kk];
      short8 Bl = *(const short8*)&Wlt[n * KP + kk];
      acc[nt] = __builtin_amdgcn_mfma_f32_16x16x32_bf16(Al.s, Bh, acc[nt], 0, 0, 0);
      acc[nt] = __builtin_amdgcn_mfma_f32_16x16x32_bf16(Ah.s, Bl, acc[nt], 0, 0, 0);
      acc[nt] = __builtin_amdgcn_mfma_f32_16x16x32_bf16(Ah.s, Bh, acc[nt], 0, 0, 0);
    }
  }

  // --- store: D row = q*4 + reg, col = nt*16 + (lane&15) ---
  #pragma unroll
  for (int nt = 0; nt < 4; ++nt) {
    const int col = nt * 16 + nb;
    #pragma unroll
    for (int r = 0; r < 4; ++r) {
      const int row = r0 + q * 4 + r;
      xp[row * DOUT + col] = acc[nt][r];
    }
  }
}

// ---------------------------------------------------------------------------
// Kernel 2: per-node per-dim weighted median + row_sum scale + bias.
// R1 structure (proven): VGPR-addressed pipelined gathers, no readfirstlane.
// Summation order replicates reference exactly: cumsum sequential in sorted
// order, total = last cum, row_sum in original edge order.
// ---------------------------------------------------------------------------
__global__ __launch_bounds__(256) void median_kernel(
    const float* __restrict__ xp, const int* __restrict__ col,
    const float* __restrict__ ew, const float* __restrict__ bias,
    float* __restrict__ out) {
  const int wave = threadIdx.x >> 6;
  const int lane = threadIdx.x & 63;
  const int node = blockIdx.x * 4 + wave;
  if (node >= N_NODES) return;

  const int*   cp = col + node * K_DEG;
  const float* wp = ew  + node * K_DEG;

  float v[K_DEG], w[K_DEG];
  #pragma unroll
  for (int j = 0; j < K_DEG; ++j) {
    int c = cp[j];
    v[j] = xp[c * DOUT + lane];       // 256B coalesced gather, pipelined
    w[j] = wp[j];
  }

  // row_sum: original edge order (matches segment_sum)
  float rs = 0.f;
  #pragma unroll
  for (int j = 0; j < K_DEG; ++j) rs += w[j];

  // sort (v,w) pairs by v ascending — compile-time Batcher network
  constexpr NetArr<NP17> NET = net_pairs<NP17>(K_DEG);
  #pragma unroll
  for (int s = 0; s < NP17; ++s) {
    const int a = NET.v[s].a, b = NET.v[s].b;
    float va = v[a], vb = v[b];
    bool sw = vb < va;
    float wa = w[a], wb = w[b];
    v[a] = sw ? vb : va;  v[b] = sw ? va : vb;
    w[a] = sw ? wb : wa;  w[b] = sw ? wa : wb;
  }

  // sequential cumsum in sorted order (exact reference order)
  float c[K_DEG];
  float run = 0.f;
  #pragma unroll
  for (int j = 0; j < K_DEG; ++j) { run += w[j]; c[j] = run; }
  const float half = 0.5f * run;

  // first sorted position with cum >= half: backward cndmask scan
  float med = v[K_DEG - 1];
  #pragma unroll
  for (int j = K_DEG - 2; j >= 0; --j)
    med = (c[j] >= half) ? v[j] : med;

  out[node * DOUT + lane] = rs * med + bias[lane];
}

// ---------------------------------------------------------------------------
extern "C" void kernel_launch(void* const* d_in, const int* in_sizes, int n_in,
                              void* d_out, int out_size, void* d_ws, size_t ws_size,
                              hipStream_t stream) {
  const float* x    = (const float*)d_in[0];
  const int*   ei   = (const int*)d_in[1];
  const float* ew   = (const float*)d_in[2];
  const float* W    = (const float*)d_in[3];
  const float* bias = (const float*)d_in[4];
  float*       out  = (float*)d_out;
  float*       xp   = (float*)d_ws;                  // 50000*64*4 = 12.8 MB
  const int*   colp = ei + (size_t)N_NODES * K_DEG;  // edge_index[1]

  const int nwaves = N_NODES / 16;                   // 3125
  gemm_kernel<<<(nwaves + 3) / 4, 256, 0, stream>>>(x, W, xp);
  median_kernel<<<(N_NODES + 3) / 4, 256, 0, stream>>>(xp, colp, ew, bias, out);
}